// Round 6
// baseline (1062.266 us; speedup 1.0000x reference)
//
#include <hip/hip_runtime.h>
#include <math.h>

#define NEG_SLOPE 0.2f
#define BN_EPS 1e-5f

// ---------------------------------------------------------------------------
// hist + graph-counts merged (both are independent histograms).
// ---------------------------------------------------------------------------
__global__ __launch_bounds__(256) void hist_kernel(
    const int* __restrict__ dst, const int* __restrict__ batch,
    int* __restrict__ deg, float* __restrict__ counts, int E_, int N_) {
  int i = blockIdx.x * 256 + threadIdx.x;
  if (i < E_) atomicAdd(&deg[dst[i]], 1);
  if (i < N_) atomicAdd(&counts[batch[i]], 1.0f);
}

// ---------------------------------------------------------------------------
// Single-block scan over deg -> row_ptr/cursor, int4-vectorized.
// ---------------------------------------------------------------------------
__global__ __launch_bounds__(256) void scan_kernel(
    const int* __restrict__ deg, int* __restrict__ row_ptr,
    int* __restrict__ cursor, int N_, int E_) {
  __shared__ int partials[256];
  int t = threadIdx.x;
  int slice = (((N_ + 255) / 256) + 3) & ~3;  // multiple of 4
  int s0 = min(t * slice, N_), s1 = min(s0 + slice, N_);
  int sum = 0;
  int i = s0;
  for (; i + 4 <= s1; i += 4) {
    int4 dv = *(const int4*)(deg + i);
    sum += dv.x + dv.y + dv.z + dv.w;
  }
  for (; i < s1; i++) sum += deg[i];
  partials[t] = sum;
  __syncthreads();
  for (int off = 1; off < 256; off <<= 1) {  // Hillis-Steele inclusive
    int v = (t >= off) ? partials[t - off] : 0;
    __syncthreads();
    partials[t] += v;
    __syncthreads();
  }
  int run = (t == 0) ? 0 : partials[t - 1];
  i = s0;
  for (; i + 4 <= s1; i += 4) {
    int4 dv = *(const int4*)(deg + i);
    int4 rp;
    rp.x = run;
    rp.y = run + dv.x;
    rp.z = rp.y + dv.y;
    rp.w = rp.z + dv.z;
    *(int4*)(row_ptr + i) = rp;
    *(int4*)(cursor + i) = rp;
    run = rp.w + dv.w;
  }
  for (; i < s1; i++) {
    row_ptr[i] = run;
    cursor[i] = run;
    run += deg[i];
  }
  if (t == 255) row_ptr[N_] = E_;
}

__global__ __launch_bounds__(256) void scatter_kernel(
    const int* __restrict__ src, const int* __restrict__ dst,
    int* __restrict__ cursor, int2* __restrict__ csr_se, int E_) {
  int e = blockIdx.x * 256 + threadIdx.x;
  if (e >= E_) return;
  int pos = atomicAdd(&cursor[dst[e]], 1);
  csr_se[pos] = make_int2(src[e], e);
}

// ---------------------------------------------------------------------------
// Node linear 64->64 (embedding). W column in registers, broadcast row loads.
// ---------------------------------------------------------------------------
__global__ __launch_bounds__(256) void linear64_kernel(
    const float* __restrict__ in, const float* __restrict__ W,
    const float* __restrict__ bias, float* __restrict__ out, int rows) {
  int o = threadIdx.x & 63;
  float4 Wreg[16];
#pragma unroll
  for (int q = 0; q < 16; q++) Wreg[q] = ((const float4*)(W + o * 64))[q];
  float b = bias[o];
  int gw = (blockIdx.x * 256 + threadIdx.x) >> 6;
  int nw = gridDim.x * 4;
  for (int n = gw; n < rows; n += nw) {
    const float4* xp = (const float4*)(in + (size_t)n * 64);
    float acc = b;
#pragma unroll
    for (int q = 0; q < 16; q++) {
      float4 xv = xp[q];
      acc += xv.x * Wreg[q].x + xv.y * Wreg[q].y + xv.z * Wreg[q].z +
             xv.w * Wreg[q].w;
    }
    out[(size_t)n * 64 + o] = acc;
  }
}

// ---------------------------------------------------------------------------
// Fused xl/xr: both weight rows in registers, 2-node unroll for MLP.
// ---------------------------------------------------------------------------
__global__ __launch_bounds__(256) void linear64x2_kernel(
    const float* __restrict__ in, const float* __restrict__ Wl,
    const float* __restrict__ bl, const float* __restrict__ Wr,
    const float* __restrict__ br, float* __restrict__ xl,
    float* __restrict__ xr, int rows) {
  int o = threadIdx.x & 63;
  float4 WL[16], WR[16];
#pragma unroll
  for (int q = 0; q < 16; q++) {
    WL[q] = ((const float4*)(Wl + o * 64))[q];
    WR[q] = ((const float4*)(Wr + o * 64))[q];
  }
  float b0 = bl[o], b1 = br[o];
  int gw = (blockIdx.x * 256 + threadIdx.x) >> 6;
  int nw = gridDim.x * 4;
  for (int n = gw; n < rows; n += 2 * nw) {
    int n2 = n + nw;
    const float4* xp = (const float4*)(in + (size_t)n * 64);
    const float4* yp =
        (n2 < rows) ? (const float4*)(in + (size_t)n2 * 64) : xp;
    float a0 = b0, a1 = b1, c0 = b0, c1 = b1;
#pragma unroll
    for (int q = 0; q < 16; q++) {
      float4 xv = xp[q];
      float4 yv = yp[q];
      a0 += xv.x * WL[q].x + xv.y * WL[q].y + xv.z * WL[q].z + xv.w * WL[q].w;
      a1 += xv.x * WR[q].x + xv.y * WR[q].y + xv.z * WR[q].z + xv.w * WR[q].w;
      c0 += yv.x * WL[q].x + yv.y * WL[q].y + yv.z * WL[q].z + yv.w * WL[q].w;
      c1 += yv.x * WR[q].x + yv.y * WR[q].y + yv.z * WR[q].z + yv.w * WR[q].w;
    }
    xl[(size_t)n * 64 + o] = a0;
    xr[(size_t)n * 64 + o] = a1;
    if (n2 < rows) {
      xl[(size_t)n2 * 64 + o] = c0;
      xr[(size_t)n2 * 64 + o] = c1;
    }
  }
}

// ---------------------------------------------------------------------------
// Fused GATv2 layer, PACKED: wave = 4 groups x 16 lanes; group g owns edge
// base+g / base+4+g of the chunk; lane (g,p) owns features 4p..4p+3.
// Shuffle reductions are width-16 (shared by 4 edges); attr broadcast via
// width-16 shfl from one coalesced load. Online softmax with chunk-shared
// running max; per-group partial (l, acc) combined at the end.
// Epilogue: folded conv_bias+BN as val*scale+shift, exact GELU, residual.
// ---------------------------------------------------------------------------
__global__ __launch_bounds__(256) void gat_fused_kernel(
    const int2* __restrict__ csr_se, const int* __restrict__ row_ptr,
    const float* __restrict__ edge_attr, const float* __restrict__ xl,
    const float* __restrict__ xr, const float* __restrict__ We,
    const float* __restrict__ att, const float* __restrict__ conv_bias,
    const float* __restrict__ gamma, const float* __restrict__ beta,
    const float* __restrict__ mean, const float* __restrict__ var,
    float* __restrict__ h, int N_) {
  int lane = threadIdx.x & 63;
  int g = lane >> 4, p = lane & 15;
  int f0 = p * 4;
  int gwave = (blockIdx.x * 256 + threadIdx.x) >> 6;
  int nwaves = gridDim.x * 4;
  float4 Wef[16];  // Wef[k] = We[f0+r][k], r=0..3 (column gather, 4KB -> L1)
#pragma unroll
  for (int k = 0; k < 16; k++) {
    Wef[k].x = We[(f0 + 0) * 16 + k];
    Wef[k].y = We[(f0 + 1) * 16 + k];
    Wef[k].z = We[(f0 + 2) * 16 + k];
    Wef[k].w = We[(f0 + 3) * 16 + k];
  }
  float4 attv = *(const float4*)(att + f0);
  float4 cb = *(const float4*)(conv_bias + f0);
  float4 gav = *(const float4*)(gamma + f0);
  float4 bev = *(const float4*)(beta + f0);
  float4 muv = *(const float4*)(mean + f0);
  float4 vav = *(const float4*)(var + f0);
  float4 sc4, sh4;  // val = agg*sc4 + sh4  (conv_bias+BN folded)
  sc4.x = rsqrtf(vav.x + BN_EPS) * gav.x;
  sc4.y = rsqrtf(vav.y + BN_EPS) * gav.y;
  sc4.z = rsqrtf(vav.z + BN_EPS) * gav.z;
  sc4.w = rsqrtf(vav.w + BN_EPS) * gav.w;
  sh4.x = (cb.x - muv.x) * sc4.x + bev.x;
  sh4.y = (cb.y - muv.y) * sc4.y + bev.y;
  sh4.z = (cb.z - muv.z) * sc4.z + bev.z;
  sh4.w = (cb.w - muv.w) * sc4.w + bev.w;
  for (int d = gwave; d < N_; d += nwaves) {
    int beg = __builtin_amdgcn_readfirstlane(row_ptr[d]);
    int end = __builtin_amdgcn_readfirstlane(row_ptr[d + 1]);
    float4 xr4 = *(const float4*)(xr + (size_t)d * 64 + f0);
    float4 h4 = *(const float4*)(h + (size_t)d * 64 + f0);
    float m = -INFINITY, l = 0.f;
    float4 acc = make_float4(0.f, 0.f, 0.f, 0.f);
    for (int base = beg; base < end; base += 8) {
      int iA = min(base + g, end - 1);
      int iB = min(base + 4 + g, end - 1);
      int2 seA = csr_se[iA];
      int2 seB = csr_se[iB];
      float aA = edge_attr[(size_t)seA.y * 16 + p];
      float aB = edge_attr[(size_t)seB.y * 16 + p];
      float4 xA = *(const float4*)(xl + (size_t)seA.x * 64 + f0);
      float4 xB = *(const float4*)(xl + (size_t)seB.x * 64 + f0);
      float4 eaA = make_float4(0.f, 0.f, 0.f, 0.f);
      float4 eaB = make_float4(0.f, 0.f, 0.f, 0.f);
#pragma unroll
      for (int k = 0; k < 16; k++) {
        float bA = __shfl(aA, k, 16);
        float bB = __shfl(aB, k, 16);
        eaA.x += bA * Wef[k].x; eaA.y += bA * Wef[k].y;
        eaA.z += bA * Wef[k].z; eaA.w += bA * Wef[k].w;
        eaB.x += bB * Wef[k].x; eaB.y += bB * Wef[k].y;
        eaB.z += bB * Wef[k].z; eaB.w += bB * Wef[k].w;
      }
      float z, vA = 0.f, vB = 0.f;
      z = xA.x + xr4.x + eaA.x; z = (z > 0.f) ? z : NEG_SLOPE * z; vA += z * attv.x;
      z = xA.y + xr4.y + eaA.y; z = (z > 0.f) ? z : NEG_SLOPE * z; vA += z * attv.y;
      z = xA.z + xr4.z + eaA.z; z = (z > 0.f) ? z : NEG_SLOPE * z; vA += z * attv.z;
      z = xA.w + xr4.w + eaA.w; z = (z > 0.f) ? z : NEG_SLOPE * z; vA += z * attv.w;
      z = xB.x + xr4.x + eaB.x; z = (z > 0.f) ? z : NEG_SLOPE * z; vB += z * attv.x;
      z = xB.y + xr4.y + eaB.y; z = (z > 0.f) ? z : NEG_SLOPE * z; vB += z * attv.y;
      z = xB.z + xr4.z + eaB.z; z = (z > 0.f) ? z : NEG_SLOPE * z; vB += z * attv.z;
      z = xB.w + xr4.w + eaB.w; z = (z > 0.f) ? z : NEG_SLOPE * z; vB += z * attv.w;
#pragma unroll
      for (int off = 1; off < 16; off <<= 1) {
        vA += __shfl_xor(vA, off);
        vB += __shfl_xor(vB, off);
      }
      vA = (base + g < end) ? vA : -INFINITY;
      vB = (base + 4 + g < end) ? vB : -INFINITY;
      float mg = fmaxf(vA, vB);
      mg = fmaxf(mg, __shfl_xor(mg, 16));
      mg = fmaxf(mg, __shfl_xor(mg, 32));
      float newm = fmaxf(m, mg);
      float s = __expf(m - newm);  // first chunk: exp(-inf)=0
      float wA = __expf(vA - newm);
      float wB = __expf(vB - newm);
      l = l * s + wA + wB;
      acc.x = acc.x * s + wA * xA.x + wB * xB.x;
      acc.y = acc.y * s + wA * xA.y + wB * xB.y;
      acc.z = acc.z * s + wA * xA.z + wB * xB.z;
      acc.w = acc.w * s + wA * xA.w + wB * xB.w;
      m = newm;
    }
    // combine the 4 per-group partials (consistent scaling via shared m)
    l += __shfl_xor(l, 16); l += __shfl_xor(l, 32);
    acc.x += __shfl_xor(acc.x, 16); acc.x += __shfl_xor(acc.x, 32);
    acc.y += __shfl_xor(acc.y, 16); acc.y += __shfl_xor(acc.y, 32);
    acc.z += __shfl_xor(acc.z, 16); acc.z += __shfl_xor(acc.z, 32);
    acc.w += __shfl_xor(acc.w, 16); acc.w += __shfl_xor(acc.w, 32);
    float inv = 1.f / (l + 1e-16f);
    float4 o4;
    o4.x = acc.x * inv * sc4.x + sh4.x;
    o4.y = acc.y * inv * sc4.y + sh4.y;
    o4.z = acc.z * inv * sc4.z + sh4.z;
    o4.w = acc.w * inv * sc4.w + sh4.w;
    o4.x = 0.5f * o4.x * (1.f + erff(o4.x * 0.70710678118654752f));
    o4.y = 0.5f * o4.y * (1.f + erff(o4.y * 0.70710678118654752f));
    o4.z = 0.5f * o4.z * (1.f + erff(o4.z * 0.70710678118654752f));
    o4.w = 0.5f * o4.w * (1.f + erff(o4.w * 0.70710678118654752f));
    if (g == 0) {
      float4 hn;
      hn.x = h4.x + o4.x;
      hn.y = h4.y + o4.y;
      hn.z = h4.z + o4.z;
      hn.w = h4.w + o4.w;
      *(float4*)(h + (size_t)d * 64 + f0) = hn;
    }
  }
}

// ---------------------------------------------------------------------------
// Final: out128 = h @ lin_W.T + lin_b, pooled per graph (batch sorted).
// ---------------------------------------------------------------------------
__global__ __launch_bounds__(256) void lin_pool_kernel(
    const float* __restrict__ h, const float* __restrict__ lin_W,
    const float* __restrict__ lin_b, const int* __restrict__ batch,
    float* __restrict__ pooled, int rows) {
  int o = threadIdx.x & 127;
  int slot = threadIdx.x >> 7;
  float4 Wreg[16];
#pragma unroll
  for (int q = 0; q < 16; q++) Wreg[q] = ((const float4*)(lin_W + o * 64))[q];
  float b = lin_b[o];
  int node0 = blockIdx.x * 64;
  float acc = 0.f;
  int curg = -1;
  for (int c = slot; c < 64; c += 2) {
    int n = node0 + c;
    if (n >= rows) break;
    const float4* hp = (const float4*)(h + (size_t)n * 64);
    float dot = b;
#pragma unroll
    for (int q = 0; q < 16; q++) {
      float4 xv = hp[q];
      dot += xv.x * Wreg[q].x + xv.y * Wreg[q].y + xv.z * Wreg[q].z +
             xv.w * Wreg[q].w;
    }
    int gq = batch[n];
    if (gq != curg) {
      if (curg >= 0) atomicAdd(&pooled[curg * 128 + o], acc);
      acc = 0.f;
      curg = gq;
    }
    acc += dot;
  }
  if (curg >= 0) atomicAdd(&pooled[curg * 128 + o], acc);
}

__global__ __launch_bounds__(256) void normalize_kernel(
    float* __restrict__ pooled, const float* __restrict__ counts, int total) {
  int idx = blockIdx.x * 256 + threadIdx.x;
  if (idx < total) pooled[idx] /= fmaxf(counts[idx >> 7], 1.0f);
}

extern "C" void kernel_launch(void* const* d_in, const int* in_sizes, int n_in,
                              void* d_out, int out_size, void* d_ws, size_t ws_size,
                              hipStream_t stream) {
  const float* x         = (const float*)d_in[0];
  const int*   edge_index= (const int*)  d_in[1];
  const float* edge_attr = (const float*)d_in[2];
  const int*   batch     = (const int*)  d_in[3];
  const float* emb_W     = (const float*)d_in[4];
  const float* emb_b     = (const float*)d_in[5];
  const float* Wl        = (const float*)d_in[6];
  const float* bl        = (const float*)d_in[7];
  const float* Wr        = (const float*)d_in[8];
  const float* br        = (const float*)d_in[9];
  const float* We        = (const float*)d_in[10];
  const float* att       = (const float*)d_in[11];
  const float* conv_bias = (const float*)d_in[12];
  const float* bn_gamma  = (const float*)d_in[13];
  const float* bn_beta   = (const float*)d_in[14];
  const float* bn_mean   = (const float*)d_in[15];
  const float* bn_var    = (const float*)d_in[16];
  const float* lin_W     = (const float*)d_in[17];
  const float* lin_b     = (const float*)d_in[18];

  const int N_ = in_sizes[0] / 64;
  const int E_ = in_sizes[1] / 2;
  const int G_ = out_size / 128;
  const int* src = edge_index;
  const int* dst = edge_index + E_;

  const int Npad = (N_ + 3) & ~3;

  // Workspace layout (16B-aligned segments), ~45 MB total.
  float* ws      = (float*)d_ws;
  float* h       = ws;                                 // N*64
  float* xl      = h  + (size_t)N_ * 64;               // N*64
  float* xr      = xl + (size_t)N_ * 64;               // N*64
  int2*  csr_se  = (int2*)(xr + (size_t)N_ * 64);      // E
  int*   row_ptr = (int*)(csr_se + E_);                // N+1 (padded)
  int*   cursor  = row_ptr + (Npad + 4);               // N (padded)
  int*   deg     = cursor + Npad;                      // N (padded)
  float* counts  = (float*)(deg + Npad);               // G  (contiguous w/ deg)

  const int hgrid = (max(E_, N_) + 255) / 256;

  // --- CSR build + graph counts (once per call, reused by all 3 layers) ---
  hipMemsetAsync(deg, 0, ((size_t)Npad + G_) * 4, stream);  // deg + counts
  hist_kernel<<<hgrid, 256, 0, stream>>>(dst, batch, deg, counts, E_, N_);
  scan_kernel<<<1, 256, 0, stream>>>(deg, row_ptr, cursor, N_, E_);
  scatter_kernel<<<(E_ + 255) / 256, 256, 0, stream>>>(src, dst, cursor,
                                                       csr_se, E_);

  // h = x @ emb_W.T + emb_b
  linear64_kernel<<<1024, 256, 0, stream>>>(x, emb_W, emb_b, h, N_);

  for (int l = 0; l < 3; l++) {
    linear64x2_kernel<<<1024, 256, 0, stream>>>(
        h, Wl + (size_t)l * 4096, bl + l * 64, Wr + (size_t)l * 4096,
        br + l * 64, xl, xr, N_);
    gat_fused_kernel<<<4096, 256, 0, stream>>>(
        csr_se, row_ptr, edge_attr, xl, xr, We + (size_t)l * 1024,
        att + l * 64, conv_bias + l * 64, bn_gamma + l * 64, bn_beta + l * 64,
        bn_mean + l * 64, bn_var + l * 64, h, N_);
  }

  hipMemsetAsync(d_out, 0, (size_t)G_ * 128 * 4, stream);
  lin_pool_kernel<<<(N_ + 63) / 64, 256, 0, stream>>>(h, lin_W, lin_b, batch,
                                                      (float*)d_out, N_);
  normalize_kernel<<<(G_ * 128 + 255) / 256, 256, 0, stream>>>(
      (float*)d_out, counts, G_ * 128);
}

// Round 7
// 893.226 us; speedup vs baseline: 1.1892x; 1.1892x over previous
//
#include <hip/hip_runtime.h>
#include <math.h>

#define NEG_SLOPE 0.2f
#define BN_EPS 1e-5f

// ---------------------------------------------------------------------------
// VALU-only 64-lane sum: 4 DPP row-rotate adds (within 16-lane rows) + 2
// cross-row shuffles. Replaces the 6-deep ds_swizzle butterfly.
// ---------------------------------------------------------------------------
__device__ __forceinline__ float wave_sum64(float v) {
  int x;
  x = __builtin_amdgcn_update_dpp(0, __float_as_int(v), 0x121, 0xF, 0xF, true);
  v += __int_as_float(x);  // row_ror:1
  x = __builtin_amdgcn_update_dpp(0, __float_as_int(v), 0x122, 0xF, 0xF, true);
  v += __int_as_float(x);  // row_ror:2
  x = __builtin_amdgcn_update_dpp(0, __float_as_int(v), 0x124, 0xF, 0xF, true);
  v += __int_as_float(x);  // row_ror:4
  x = __builtin_amdgcn_update_dpp(0, __float_as_int(v), 0x128, 0xF, 0xF, true);
  v += __int_as_float(x);  // row_ror:8 -> each 16-row holds its row sum
  v += __shfl_xor(v, 16, 64);
  v += __shfl_xor(v, 32, 64);
  return v;
}

// ---------------------------------------------------------------------------
// hist + graph-counts merged (both are independent histograms).
// ---------------------------------------------------------------------------
__global__ __launch_bounds__(256) void hist_kernel(
    const int* __restrict__ dst, const int* __restrict__ batch,
    int* __restrict__ deg, float* __restrict__ counts, int E_, int N_) {
  int i = blockIdx.x * 256 + threadIdx.x;
  if (i < E_) atomicAdd(&deg[dst[i]], 1);
  if (i < N_) atomicAdd(&counts[batch[i]], 1.0f);
}

// ---------------------------------------------------------------------------
// Single-block scan over deg -> row_ptr/cursor, int4-vectorized.
// ---------------------------------------------------------------------------
__global__ __launch_bounds__(256) void scan_kernel(
    const int* __restrict__ deg, int* __restrict__ row_ptr,
    int* __restrict__ cursor, int N_, int E_) {
  __shared__ int partials[256];
  int t = threadIdx.x;
  int slice = (((N_ + 255) / 256) + 3) & ~3;
  int s0 = min(t * slice, N_), s1 = min(s0 + slice, N_);
  int sum = 0;
  int i = s0;
  for (; i + 4 <= s1; i += 4) {
    int4 dv = *(const int4*)(deg + i);
    sum += dv.x + dv.y + dv.z + dv.w;
  }
  for (; i < s1; i++) sum += deg[i];
  partials[t] = sum;
  __syncthreads();
  for (int off = 1; off < 256; off <<= 1) {
    int v = (t >= off) ? partials[t - off] : 0;
    __syncthreads();
    partials[t] += v;
    __syncthreads();
  }
  int run = (t == 0) ? 0 : partials[t - 1];
  i = s0;
  for (; i + 4 <= s1; i += 4) {
    int4 dv = *(const int4*)(deg + i);
    int4 rp;
    rp.x = run;
    rp.y = run + dv.x;
    rp.z = rp.y + dv.y;
    rp.w = rp.z + dv.z;
    *(int4*)(row_ptr + i) = rp;
    *(int4*)(cursor + i) = rp;
    run = rp.w + dv.w;
  }
  for (; i < s1; i++) {
    row_ptr[i] = run;
    cursor[i] = run;
    run += deg[i];
  }
  if (t == 255) row_ptr[N_] = E_;
}

__global__ __launch_bounds__(256) void scatter_kernel(
    const int* __restrict__ src, const int* __restrict__ dst,
    int* __restrict__ cursor, int* __restrict__ csr_src,
    int* __restrict__ csr_eid, int E_) {
  int e = blockIdx.x * 256 + threadIdx.x;
  if (e >= E_) return;
  int pos = atomicAdd(&cursor[dst[e]], 1);
  csr_src[pos] = src[e];
  csr_eid[pos] = e;
}

// Permute edge_attr into CSR order (once per call): coalesced write, 16B
// gather read. Enables contiguous scalar attr loads in the fused kernel.
__global__ __launch_bounds__(256) void permute_attr_kernel(
    const float4* __restrict__ edge_attr4, const int* __restrict__ csr_eid,
    float4* __restrict__ attr_csr, int E_) {
  int i = blockIdx.x * 256 + threadIdx.x;
  if (i >= E_ * 4) return;
  int e = i >> 2, q = i & 3;
  attr_csr[i] = edge_attr4[csr_eid[e] * 4 + q];
}

// ---------------------------------------------------------------------------
// Node linear 64->64 (embedding). W column in registers, broadcast row loads.
// ---------------------------------------------------------------------------
__global__ __launch_bounds__(256) void linear64_kernel(
    const float* __restrict__ in, const float* __restrict__ W,
    const float* __restrict__ bias, float* __restrict__ out, int rows) {
  int o = threadIdx.x & 63;
  float4 Wreg[16];
#pragma unroll
  for (int q = 0; q < 16; q++) Wreg[q] = ((const float4*)(W + o * 64))[q];
  float b = bias[o];
  int gw = (blockIdx.x * 256 + threadIdx.x) >> 6;
  int nw = gridDim.x * 4;
  for (int n = gw; n < rows; n += nw) {
    const float4* xp = (const float4*)(in + (size_t)n * 64);
    float acc = b;
#pragma unroll
    for (int q = 0; q < 16; q++) {
      float4 xv = xp[q];
      acc += xv.x * Wreg[q].x + xv.y * Wreg[q].y + xv.z * Wreg[q].z +
             xv.w * Wreg[q].w;
    }
    out[(size_t)n * 64 + o] = acc;
  }
}

// ---------------------------------------------------------------------------
// Fused xl/xr: both weight rows in registers, 2-node unroll.
// ---------------------------------------------------------------------------
__global__ __launch_bounds__(256) void linear64x2_kernel(
    const float* __restrict__ in, const float* __restrict__ Wl,
    const float* __restrict__ bl, const float* __restrict__ Wr,
    const float* __restrict__ br, float* __restrict__ xl,
    float* __restrict__ xr, int rows) {
  int o = threadIdx.x & 63;
  float4 WL[16], WR[16];
#pragma unroll
  for (int q = 0; q < 16; q++) {
    WL[q] = ((const float4*)(Wl + o * 64))[q];
    WR[q] = ((const float4*)(Wr + o * 64))[q];
  }
  float b0 = bl[o], b1 = br[o];
  int gw = (blockIdx.x * 256 + threadIdx.x) >> 6;
  int nw = gridDim.x * 4;
  for (int n = gw; n < rows; n += 2 * nw) {
    int n2 = n + nw;
    const float4* xp = (const float4*)(in + (size_t)n * 64);
    const float4* yp =
        (n2 < rows) ? (const float4*)(in + (size_t)n2 * 64) : xp;
    float a0 = b0, a1 = b1, c0 = b0, c1 = b1;
#pragma unroll
    for (int q = 0; q < 16; q++) {
      float4 xv = xp[q];
      float4 yv = yp[q];
      a0 += xv.x * WL[q].x + xv.y * WL[q].y + xv.z * WL[q].z + xv.w * WL[q].w;
      a1 += xv.x * WR[q].x + xv.y * WR[q].y + xv.z * WR[q].z + xv.w * WR[q].w;
      c0 += yv.x * WL[q].x + yv.y * WL[q].y + yv.z * WL[q].z + yv.w * WL[q].w;
      c1 += yv.x * WR[q].x + yv.y * WR[q].y + yv.z * WR[q].z + yv.w * WR[q].w;
    }
    xl[(size_t)n * 64 + o] = a0;
    xr[(size_t)n * 64 + o] = a1;
    if (n2 < rows) {
      xl[(size_t)n2 * 64 + o] = c0;
      xr[(size_t)n2 * 64 + o] = c1;
    }
  }
}

// ---------------------------------------------------------------------------
// Fused GATv2 layer: one wave per dst node, lane j owns feature j (round-5
// structure). CH=16 edges per chunk (avg degree = 16 -> usually one chunk):
//   - csr indices via wave-uniform scalar loads,
//   - attr via wave-uniform (scalar) 64B loads -> ea = 16 v_fma w/ SGPR srcs,
//     NO LDS round-trip,
//   - 16 independent xl gathers in flight,
//   - dot reduction via DPP (VALU) + 2 shuffles instead of 6 ds_swizzles.
// Online softmax across chunks; epilogue = folded conv_bias+BN, exact GELU,
// residual.
// ---------------------------------------------------------------------------
#define CH 16
template <bool CONTIG>
__global__ __launch_bounds__(256) void gat_fused_kernel(
    const int* __restrict__ csr_src, const int* __restrict__ csr_eid,
    const int* __restrict__ row_ptr, const float* __restrict__ attr,
    const float* __restrict__ xl, const float* __restrict__ xr,
    const float* __restrict__ We, const float* __restrict__ att,
    const float* __restrict__ conv_bias, const float* __restrict__ gamma,
    const float* __restrict__ beta, const float* __restrict__ mean,
    const float* __restrict__ var, float* __restrict__ h, int N_) {
  int j = threadIdx.x & 63;
  int gwave = (blockIdx.x * 256 + threadIdx.x) >> 6;
  int nwaves = gridDim.x * 4;
  float Wek[16];
#pragma unroll
  for (int k = 0; k < 16; k++) Wek[k] = We[j * 16 + k];
  float att_j = att[j];
  float sc = rsqrtf(var[j] + BN_EPS) * gamma[j];
  float sh = (conv_bias[j] - mean[j]) * sc + beta[j];
  for (int d = gwave; d < N_; d += nwaves) {
    int beg = __builtin_amdgcn_readfirstlane(row_ptr[d]);
    int end = __builtin_amdgcn_readfirstlane(row_ptr[d + 1]);
    float xrj = xr[(size_t)d * 64 + j];
    float m = -INFINITY, l = 0.f, acc = 0.f;
    for (int base = beg; base < end; base += CH) {
      // wave-uniform index loads (SGPR)
      int idxs[CH], si[CH];
#pragma unroll
      for (int t = 0; t < CH; t++) {
        idxs[t] = min(base + t, end - 1);
        si[t] = csr_src[idxs[t]];
      }
      // 16 independent gathers, all in flight
      float xlv[CH];
#pragma unroll
      for (int t = 0; t < CH; t++) xlv[t] = xl[(size_t)si[t] * 64 + j];
      float v[CH];
#pragma unroll
      for (int t = 0; t < CH; t++) {
        size_t off = CONTIG ? (size_t)idxs[t] * 16
                            : (size_t)csr_eid[idxs[t]] * 16;
        const float4* ap = (const float4*)(attr + off);  // uniform -> s_load
        float4 a0 = ap[0], a1 = ap[1], a2 = ap[2], a3 = ap[3];
        float ea = a0.x * Wek[0]  + a0.y * Wek[1]  + a0.z * Wek[2]  + a0.w * Wek[3]
                 + a1.x * Wek[4]  + a1.y * Wek[5]  + a1.z * Wek[6]  + a1.w * Wek[7]
                 + a2.x * Wek[8]  + a2.y * Wek[9]  + a2.z * Wek[10] + a2.w * Wek[11]
                 + a3.x * Wek[12] + a3.y * Wek[13] + a3.z * Wek[14] + a3.w * Wek[15];
        float z = xlv[t] + xrj + ea;
        z = fmaxf(z, NEG_SLOPE * z);  // leaky_relu(z) == max(z, 0.2z)
        float p = wave_sum64(z * att_j);
        v[t] = (base + t < end) ? p : -INFINITY;
      }
      float mc = v[0];
#pragma unroll
      for (int t = 1; t < CH; t++) mc = fmaxf(mc, v[t]);
      float newm = fmaxf(m, mc);
      float s = __expf(m - newm);  // first chunk: exp(-inf)=0
      l *= s;
      acc *= s;
#pragma unroll
      for (int t = 0; t < CH; t++) {
        float w = __expf(v[t] - newm);  // padded slots: exp(-inf)=0
        l += w;
        acc += w * xlv[t];
      }
      m = newm;
    }
    float val = acc / (l + 1e-16f) * sc + sh;  // conv_bias+BN folded
    float g = 0.5f * val * (1.f + erff(val * 0.70710678118654752f));
    h[(size_t)d * 64 + j] += g;
  }
}

// ---------------------------------------------------------------------------
// Final: out128 = h @ lin_W.T + lin_b, pooled per graph (batch sorted).
// ---------------------------------------------------------------------------
__global__ __launch_bounds__(256) void lin_pool_kernel(
    const float* __restrict__ h, const float* __restrict__ lin_W,
    const float* __restrict__ lin_b, const int* __restrict__ batch,
    float* __restrict__ pooled, int rows) {
  int o = threadIdx.x & 127;
  int slot = threadIdx.x >> 7;
  float4 Wreg[16];
#pragma unroll
  for (int q = 0; q < 16; q++) Wreg[q] = ((const float4*)(lin_W + o * 64))[q];
  float b = lin_b[o];
  int node0 = blockIdx.x * 64;
  float acc = 0.f;
  int curg = -1;
  for (int c = slot; c < 64; c += 2) {
    int n = node0 + c;
    if (n >= rows) break;
    const float4* hp = (const float4*)(h + (size_t)n * 64);
    float dot = b;
#pragma unroll
    for (int q = 0; q < 16; q++) {
      float4 xv = hp[q];
      dot += xv.x * Wreg[q].x + xv.y * Wreg[q].y + xv.z * Wreg[q].z +
             xv.w * Wreg[q].w;
    }
    int gq = batch[n];
    if (gq != curg) {
      if (curg >= 0) atomicAdd(&pooled[curg * 128 + o], acc);
      acc = 0.f;
      curg = gq;
    }
    acc += dot;
  }
  if (curg >= 0) atomicAdd(&pooled[curg * 128 + o], acc);
}

__global__ __launch_bounds__(256) void normalize_kernel(
    float* __restrict__ pooled, const float* __restrict__ counts, int total) {
  int idx = blockIdx.x * 256 + threadIdx.x;
  if (idx < total) pooled[idx] /= fmaxf(counts[idx >> 7], 1.0f);
}

extern "C" void kernel_launch(void* const* d_in, const int* in_sizes, int n_in,
                              void* d_out, int out_size, void* d_ws, size_t ws_size,
                              hipStream_t stream) {
  const float* x         = (const float*)d_in[0];
  const int*   edge_index= (const int*)  d_in[1];
  const float* edge_attr = (const float*)d_in[2];
  const int*   batch     = (const int*)  d_in[3];
  const float* emb_W     = (const float*)d_in[4];
  const float* emb_b     = (const float*)d_in[5];
  const float* Wl        = (const float*)d_in[6];
  const float* bl        = (const float*)d_in[7];
  const float* Wr        = (const float*)d_in[8];
  const float* br        = (const float*)d_in[9];
  const float* We        = (const float*)d_in[10];
  const float* att       = (const float*)d_in[11];
  const float* conv_bias = (const float*)d_in[12];
  const float* bn_gamma  = (const float*)d_in[13];
  const float* bn_beta   = (const float*)d_in[14];
  const float* bn_mean   = (const float*)d_in[15];
  const float* bn_var    = (const float*)d_in[16];
  const float* lin_W     = (const float*)d_in[17];
  const float* lin_b     = (const float*)d_in[18];

  const int N_ = in_sizes[0] / 64;
  const int E_ = in_sizes[1] / 2;
  const int G_ = out_size / 128;
  const int* src = edge_index;
  const int* dst = edge_index + E_;

  const int Npad = (N_ + 3) & ~3;
  const int Epad = (E_ + 19) & ~3;  // slack for clamped tail reads

  // Workspace layout (floats). attr_csr last so the base set fits small ws.
  float* ws      = (float*)d_ws;
  float* h       = ws;                                 // N*64
  float* xl      = h  + (size_t)N_ * 64;               // N*64
  float* xr      = xl + (size_t)N_ * 64;               // N*64
  int*   csr_src = (int*)(xr + (size_t)N_ * 64);       // Epad
  int*   csr_eid = csr_src + Epad;                     // Epad
  int*   row_ptr = csr_eid + Epad;                     // Npad+4
  int*   cursor  = row_ptr + (Npad + 4);               // Npad
  int*   deg     = cursor + Npad;                      // Npad
  float* counts  = (float*)(deg + Npad);               // G
  float* attr_csr= counts + G_;                        // E*16 (optional)

  size_t base_elems = (size_t)N_ * 64 * 3 + 2 * (size_t)Epad +
                      (Npad + 4) + 2 * (size_t)Npad + G_;
  bool contig = ws_size >= (base_elems + (size_t)E_ * 16) * 4;

  const int hgrid = (max(E_, N_) + 255) / 256;

  // --- CSR build + graph counts (once per call, reused by all 3 layers) ---
  hipMemsetAsync(deg, 0, ((size_t)Npad + G_) * 4, stream);  // deg + counts
  hist_kernel<<<hgrid, 256, 0, stream>>>(dst, batch, deg, counts, E_, N_);
  scan_kernel<<<1, 256, 0, stream>>>(deg, row_ptr, cursor, N_, E_);
  scatter_kernel<<<(E_ + 255) / 256, 256, 0, stream>>>(src, dst, cursor,
                                                       csr_src, csr_eid, E_);
  if (contig) {
    permute_attr_kernel<<<(E_ * 4 + 255) / 256, 256, 0, stream>>>(
        (const float4*)edge_attr, csr_eid, (float4*)attr_csr, E_);
  }

  // h = x @ emb_W.T + emb_b
  linear64_kernel<<<1024, 256, 0, stream>>>(x, emb_W, emb_b, h, N_);

  for (int l = 0; l < 3; l++) {
    linear64x2_kernel<<<1024, 256, 0, stream>>>(
        h, Wl + (size_t)l * 4096, bl + l * 64, Wr + (size_t)l * 4096,
        br + l * 64, xl, xr, N_);
    if (contig) {
      gat_fused_kernel<true><<<4096, 256, 0, stream>>>(
          csr_src, csr_eid, row_ptr, attr_csr, xl, xr,
          We + (size_t)l * 1024, att + l * 64, conv_bias + l * 64,
          bn_gamma + l * 64, bn_beta + l * 64, bn_mean + l * 64,
          bn_var + l * 64, h, N_);
    } else {
      gat_fused_kernel<false><<<4096, 256, 0, stream>>>(
          csr_src, csr_eid, row_ptr, edge_attr, xl, xr,
          We + (size_t)l * 1024, att + l * 64, conv_bias + l * 64,
          bn_gamma + l * 64, bn_beta + l * 64, bn_mean + l * 64,
          bn_var + l * 64, h, N_);
    }
  }

  hipMemsetAsync(d_out, 0, (size_t)G_ * 128 * 4, stream);
  lin_pool_kernel<<<(N_ + 63) / 64, 256, 0, stream>>>(h, lin_W, lin_b, batch,
                                                      (float*)d_out, N_);
  normalize_kernel<<<(G_ * 128 + 255) / 256, 256, 0, stream>>>(
      (float*)d_out, counts, G_ * 128);
}

// Round 8
// 847.488 us; speedup vs baseline: 1.2534x; 1.0540x over previous
//
#include <hip/hip_runtime.h>
#include <math.h>

#define NEG_SLOPE 0.2f
#define BN_EPS 1e-5f

template <int N> struct IC { static constexpr int v = N; };
template <bool B> struct BC { static constexpr bool v = B; };

// ---------------------------------------------------------------------------
// VALU-only 64-lane sum: 4 DPP row-rotate adds + 2 cross-row shuffles.
// ---------------------------------------------------------------------------
__device__ __forceinline__ float wave_sum64(float v) {
  int x;
  x = __builtin_amdgcn_update_dpp(0, __float_as_int(v), 0x121, 0xF, 0xF, true);
  v += __int_as_float(x);  // row_ror:1
  x = __builtin_amdgcn_update_dpp(0, __float_as_int(v), 0x122, 0xF, 0xF, true);
  v += __int_as_float(x);  // row_ror:2
  x = __builtin_amdgcn_update_dpp(0, __float_as_int(v), 0x124, 0xF, 0xF, true);
  v += __int_as_float(x);  // row_ror:4
  x = __builtin_amdgcn_update_dpp(0, __float_as_int(v), 0x128, 0xF, 0xF, true);
  v += __int_as_float(x);  // row_ror:8
  v += __shfl_xor(v, 16, 64);
  v += __shfl_xor(v, 32, 64);
  return v;
}

// ---------------------------------------------------------------------------
// hist + graph-counts merged.
// ---------------------------------------------------------------------------
__global__ __launch_bounds__(256) void hist_kernel(
    const int* __restrict__ dst, const int* __restrict__ batch,
    int* __restrict__ deg, float* __restrict__ counts, int E_, int N_) {
  int i = blockIdx.x * 256 + threadIdx.x;
  if (i < E_) atomicAdd(&deg[dst[i]], 1);
  if (i < N_) atomicAdd(&counts[batch[i]], 1.0f);
}

// ---------------------------------------------------------------------------
// Single-block scan over deg -> row_ptr/cursor, int4-vectorized.
// ---------------------------------------------------------------------------
__global__ __launch_bounds__(256) void scan_kernel(
    const int* __restrict__ deg, int* __restrict__ row_ptr,
    int* __restrict__ cursor, int N_, int E_) {
  __shared__ int partials[256];
  int t = threadIdx.x;
  int slice = (((N_ + 255) / 256) + 3) & ~3;
  int s0 = min(t * slice, N_), s1 = min(s0 + slice, N_);
  int sum = 0;
  int i = s0;
  for (; i + 4 <= s1; i += 4) {
    int4 dv = *(const int4*)(deg + i);
    sum += dv.x + dv.y + dv.z + dv.w;
  }
  for (; i < s1; i++) sum += deg[i];
  partials[t] = sum;
  __syncthreads();
  for (int off = 1; off < 256; off <<= 1) {
    int v = (t >= off) ? partials[t - off] : 0;
    __syncthreads();
    partials[t] += v;
    __syncthreads();
  }
  int run = (t == 0) ? 0 : partials[t - 1];
  i = s0;
  for (; i + 4 <= s1; i += 4) {
    int4 dv = *(const int4*)(deg + i);
    int4 rp;
    rp.x = run;
    rp.y = run + dv.x;
    rp.z = rp.y + dv.y;
    rp.w = rp.z + dv.z;
    *(int4*)(row_ptr + i) = rp;
    *(int4*)(cursor + i) = rp;
    run = rp.w + dv.w;
  }
  for (; i < s1; i++) {
    row_ptr[i] = run;
    cursor[i] = run;
    run += deg[i];
  }
  if (t == 255) row_ptr[N_] = E_;
}

// ---------------------------------------------------------------------------
// Scatter with fused attr permute: coalesced edge_attr read, 64B write at
// the CSR slot. Saves the separate permute pass. Fallback: write eid.
// ---------------------------------------------------------------------------
__global__ __launch_bounds__(256) void scatter_kernel(
    const int* __restrict__ src, const int* __restrict__ dst,
    const float4* __restrict__ edge_attr4, int* __restrict__ cursor,
    int* __restrict__ csr_src, int* __restrict__ csr_eid,
    float4* __restrict__ attr_csr, int E_) {
  int e = blockIdx.x * 256 + threadIdx.x;
  if (e >= E_) return;
  int pos = atomicAdd(&cursor[dst[e]], 1);
  csr_src[pos] = src[e];
  if (attr_csr) {
    float4 a0 = edge_attr4[e * 4 + 0];
    float4 a1 = edge_attr4[e * 4 + 1];
    float4 a2 = edge_attr4[e * 4 + 2];
    float4 a3 = edge_attr4[e * 4 + 3];
    attr_csr[pos * 4 + 0] = a0;
    attr_csr[pos * 4 + 1] = a1;
    attr_csr[pos * 4 + 2] = a2;
    attr_csr[pos * 4 + 3] = a3;
  } else {
    csr_eid[pos] = e;
  }
}

// ---------------------------------------------------------------------------
// Node linear 64->64 (embedding). W column in registers, broadcast row loads.
// ---------------------------------------------------------------------------
__global__ __launch_bounds__(256) void linear64_kernel(
    const float* __restrict__ in, const float* __restrict__ W,
    const float* __restrict__ bias, float* __restrict__ out, int rows) {
  int o = threadIdx.x & 63;
  float4 Wreg[16];
#pragma unroll
  for (int q = 0; q < 16; q++) Wreg[q] = ((const float4*)(W + o * 64))[q];
  float b = bias[o];
  int gw = (blockIdx.x * 256 + threadIdx.x) >> 6;
  int nw = gridDim.x * 4;
  for (int n = gw; n < rows; n += nw) {
    const float4* xp = (const float4*)(in + (size_t)n * 64);
    float acc = b;
#pragma unroll
    for (int q = 0; q < 16; q++) {
      float4 xv = xp[q];
      acc += xv.x * Wreg[q].x + xv.y * Wreg[q].y + xv.z * Wreg[q].z +
             xv.w * Wreg[q].w;
    }
    out[(size_t)n * 64 + o] = acc;
  }
}

// ---------------------------------------------------------------------------
// Fused xl/xr: both weight rows in registers, 2-node unroll.
// ---------------------------------------------------------------------------
__global__ __launch_bounds__(256) void linear64x2_kernel(
    const float* __restrict__ in, const float* __restrict__ Wl,
    const float* __restrict__ bl, const float* __restrict__ Wr,
    const float* __restrict__ br, float* __restrict__ xl,
    float* __restrict__ xr, int rows) {
  int o = threadIdx.x & 63;
  float4 WL[16], WR[16];
#pragma unroll
  for (int q = 0; q < 16; q++) {
    WL[q] = ((const float4*)(Wl + o * 64))[q];
    WR[q] = ((const float4*)(Wr + o * 64))[q];
  }
  float b0 = bl[o], b1 = br[o];
  int gw = (blockIdx.x * 256 + threadIdx.x) >> 6;
  int nw = gridDim.x * 4;
  for (int n = gw; n < rows; n += 2 * nw) {
    int n2 = n + nw;
    const float4* xp = (const float4*)(in + (size_t)n * 64);
    const float4* yp =
        (n2 < rows) ? (const float4*)(in + (size_t)n2 * 64) : xp;
    float a0 = b0, a1 = b1, c0 = b0, c1 = b1;
#pragma unroll
    for (int q = 0; q < 16; q++) {
      float4 xv = xp[q];
      float4 yv = yp[q];
      a0 += xv.x * WL[q].x + xv.y * WL[q].y + xv.z * WL[q].z + xv.w * WL[q].w;
      a1 += xv.x * WR[q].x + xv.y * WR[q].y + xv.z * WR[q].z + xv.w * WR[q].w;
      c0 += yv.x * WL[q].x + yv.y * WL[q].y + yv.z * WL[q].z + yv.w * WL[q].w;
      c1 += yv.x * WR[q].x + yv.y * WR[q].y + yv.z * WR[q].z + yv.w * WR[q].w;
    }
    xl[(size_t)n * 64 + o] = a0;
    xr[(size_t)n * 64 + o] = a1;
    if (n2 < rows) {
      xl[(size_t)n2 * 64 + o] = c0;
      xr[(size_t)n2 * 64 + o] = c1;
    }
  }
}

// ---------------------------------------------------------------------------
// Fused GATv2 layer: ONE WAVE PER NODE (fine-grained draining for load
// balance). Chunks: full-16 (no clamps) -> full-8 -> one padded-8, cutting
// padding waste ~2x vs uniform CH=16. Indices + attrs via wave-uniform
// scalar loads; 16 independent xl gathers; DPP reduction; online softmax;
// epilogue = folded conv_bias+BN, exact GELU, residual.
// ---------------------------------------------------------------------------
template <bool CONTIG>
__global__ __launch_bounds__(256) void gat_fused_kernel(
    const int* __restrict__ csr_src, const int* __restrict__ csr_eid,
    const int* __restrict__ row_ptr, const float* __restrict__ attr,
    const float* __restrict__ xl, const float* __restrict__ xr,
    const float* __restrict__ We, const float* __restrict__ att,
    const float* __restrict__ conv_bias, const float* __restrict__ gamma,
    const float* __restrict__ beta, const float* __restrict__ mean,
    const float* __restrict__ var, float* __restrict__ h, int N_) {
  int d = (blockIdx.x * 256 + threadIdx.x) >> 6;
  if (d >= N_) return;
  int j = threadIdx.x & 63;
  float Wek[16];
#pragma unroll
  for (int k = 0; k < 16; k++) Wek[k] = We[j * 16 + k];
  float att_j = att[j];
  float sc = rsqrtf(var[j] + BN_EPS) * gamma[j];
  float sh = (conv_bias[j] - mean[j]) * sc + beta[j];

  int beg = __builtin_amdgcn_readfirstlane(row_ptr[d]);
  int end = __builtin_amdgcn_readfirstlane(row_ptr[d + 1]);
  float xrj = xr[(size_t)d * 64 + j];
  float m = -INFINITY, l = 0.f, acc = 0.f;

  auto chunk = [&](int base, auto C_, auto PAD_) {
    constexpr int C = decltype(C_)::v;
    constexpr bool PAD = decltype(PAD_)::v;
    int si[C];
#pragma unroll
    for (int t = 0; t < C; t++) {
      int idx = PAD ? min(base + t, end - 1) : (base + t);
      si[t] = csr_src[idx];
    }
    float xlv[C];
#pragma unroll
    for (int t = 0; t < C; t++) xlv[t] = xl[(size_t)si[t] * 64 + j];
    float v[C];
#pragma unroll
    for (int t = 0; t < C; t++) {
      int idx = PAD ? min(base + t, end - 1) : (base + t);
      size_t off = CONTIG ? (size_t)idx * 16 : (size_t)csr_eid[idx] * 16;
      const float4* ap = (const float4*)(attr + off);  // uniform -> s_load
      float4 a0 = ap[0], a1 = ap[1], a2 = ap[2], a3 = ap[3];
      float ea = a0.x * Wek[0]  + a0.y * Wek[1]  + a0.z * Wek[2]  + a0.w * Wek[3]
               + a1.x * Wek[4]  + a1.y * Wek[5]  + a1.z * Wek[6]  + a1.w * Wek[7]
               + a2.x * Wek[8]  + a2.y * Wek[9]  + a2.z * Wek[10] + a2.w * Wek[11]
               + a3.x * Wek[12] + a3.y * Wek[13] + a3.z * Wek[14] + a3.w * Wek[15];
      float z = xlv[t] + xrj + ea;
      z = fmaxf(z, NEG_SLOPE * z);  // leaky_relu
      float p = wave_sum64(z * att_j);
      v[t] = (!PAD || (base + t < end)) ? p : -INFINITY;
    }
    float mc = v[0];
#pragma unroll
    for (int t = 1; t < C; t++) mc = fmaxf(mc, v[t]);
    float newm = fmaxf(m, mc);
    float s = __expf(m - newm);  // first chunk: exp(-inf)=0
    l *= s;
    acc *= s;
#pragma unroll
    for (int t = 0; t < C; t++) {
      float w = __expf(v[t] - newm);  // padded slots: exp(-inf)=0
      l += w;
      acc += w * xlv[t];
    }
    m = newm;
  };

  int base = beg;
  for (; base + 16 <= end; base += 16) chunk(base, IC<16>{}, BC<false>{});
  if (base + 8 <= end) {
    chunk(base, IC<8>{}, BC<false>{});
    base += 8;
  }
  if (base < end) chunk(base, IC<8>{}, BC<true>{});

  float val = acc / (l + 1e-16f) * sc + sh;  // conv_bias+BN folded
  float g = 0.5f * val * (1.f + erff(val * 0.70710678118654752f));
  h[(size_t)d * 64 + j] += g;
}

// ---------------------------------------------------------------------------
// Final: out128 = h @ lin_W.T + lin_b, pooled per graph (batch sorted),
// mean-normalization fused at flush time (counts precomputed in hist).
// ---------------------------------------------------------------------------
__global__ __launch_bounds__(256) void lin_pool_kernel(
    const float* __restrict__ h, const float* __restrict__ lin_W,
    const float* __restrict__ lin_b, const int* __restrict__ batch,
    const float* __restrict__ counts, float* __restrict__ pooled, int rows) {
  int o = threadIdx.x & 127;
  int slot = threadIdx.x >> 7;
  float4 Wreg[16];
#pragma unroll
  for (int q = 0; q < 16; q++) Wreg[q] = ((const float4*)(lin_W + o * 64))[q];
  float b = lin_b[o];
  int node0 = blockIdx.x * 64;
  float acc = 0.f;
  int curg = -1;
  for (int c = slot; c < 64; c += 2) {
    int n = node0 + c;
    if (n >= rows) break;
    const float4* hp = (const float4*)(h + (size_t)n * 64);
    float dot = b;
#pragma unroll
    for (int q = 0; q < 16; q++) {
      float4 xv = hp[q];
      dot += xv.x * Wreg[q].x + xv.y * Wreg[q].y + xv.z * Wreg[q].z +
             xv.w * Wreg[q].w;
    }
    int gq = batch[n];
    if (gq != curg) {
      if (curg >= 0)
        atomicAdd(&pooled[curg * 128 + o], acc / fmaxf(counts[curg], 1.f));
      acc = 0.f;
      curg = gq;
    }
    acc += dot;
  }
  if (curg >= 0)
    atomicAdd(&pooled[curg * 128 + o], acc / fmaxf(counts[curg], 1.f));
}

extern "C" void kernel_launch(void* const* d_in, const int* in_sizes, int n_in,
                              void* d_out, int out_size, void* d_ws, size_t ws_size,
                              hipStream_t stream) {
  const float* x         = (const float*)d_in[0];
  const int*   edge_index= (const int*)  d_in[1];
  const float* edge_attr = (const float*)d_in[2];
  const int*   batch     = (const int*)  d_in[3];
  const float* emb_W     = (const float*)d_in[4];
  const float* emb_b     = (const float*)d_in[5];
  const float* Wl        = (const float*)d_in[6];
  const float* bl        = (const float*)d_in[7];
  const float* Wr        = (const float*)d_in[8];
  const float* br        = (const float*)d_in[9];
  const float* We        = (const float*)d_in[10];
  const float* att       = (const float*)d_in[11];
  const float* conv_bias = (const float*)d_in[12];
  const float* bn_gamma  = (const float*)d_in[13];
  const float* bn_beta   = (const float*)d_in[14];
  const float* bn_mean   = (const float*)d_in[15];
  const float* bn_var    = (const float*)d_in[16];
  const float* lin_W     = (const float*)d_in[17];
  const float* lin_b     = (const float*)d_in[18];

  const int N_ = in_sizes[0] / 64;
  const int E_ = in_sizes[1] / 2;
  const int G_ = out_size / 128;
  const int* src = edge_index;
  const int* dst = edge_index + E_;

  const int Npad = (N_ + 3) & ~3;
  const int Epad = (E_ + 19) & ~3;

  // Workspace layout (floats). attr_csr last so the base set fits small ws.
  float* ws      = (float*)d_ws;
  float* h       = ws;                                 // N*64
  float* xl      = h  + (size_t)N_ * 64;               // N*64
  float* xr      = xl + (size_t)N_ * 64;               // N*64
  int*   csr_src = (int*)(xr + (size_t)N_ * 64);       // Epad
  int*   csr_eid = csr_src + Epad;                     // Epad
  int*   row_ptr = csr_eid + Epad;                     // Npad+4
  int*   cursor  = row_ptr + (Npad + 4);               // Npad
  int*   deg     = cursor + Npad;                      // Npad
  float* counts  = (float*)(deg + Npad);               // G
  float* attr_csr= counts + G_;                        // E*16 (optional)

  size_t base_elems = (size_t)N_ * 64 * 3 + 2 * (size_t)Epad +
                      (Npad + 4) + 2 * (size_t)Npad + G_;
  bool contig = ws_size >= (base_elems + (size_t)E_ * 16) * 4;

  const int hgrid = (max(E_, N_) + 255) / 256;

  // --- CSR build + graph counts (once per call, reused by all 3 layers) ---
  hipMemsetAsync(deg, 0, ((size_t)Npad + G_) * 4, stream);  // deg + counts
  hist_kernel<<<hgrid, 256, 0, stream>>>(dst, batch, deg, counts, E_, N_);
  scan_kernel<<<1, 256, 0, stream>>>(deg, row_ptr, cursor, N_, E_);
  scatter_kernel<<<(E_ + 255) / 256, 256, 0, stream>>>(
      src, dst, (const float4*)edge_attr, cursor, csr_src, csr_eid,
      contig ? (float4*)attr_csr : (float4*)nullptr, E_);

  // h = x @ emb_W.T + emb_b
  linear64_kernel<<<1024, 256, 0, stream>>>(x, emb_W, emb_b, h, N_);

  const int gatBlocks = (N_ + 3) / 4;  // one wave per node
  for (int l = 0; l < 3; l++) {
    linear64x2_kernel<<<1024, 256, 0, stream>>>(
        h, Wl + (size_t)l * 4096, bl + l * 64, Wr + (size_t)l * 4096,
        br + l * 64, xl, xr, N_);
    if (contig) {
      gat_fused_kernel<true><<<gatBlocks, 256, 0, stream>>>(
          csr_src, csr_eid, row_ptr, attr_csr, xl, xr,
          We + (size_t)l * 1024, att + l * 64, conv_bias + l * 64,
          bn_gamma + l * 64, bn_beta + l * 64, bn_mean + l * 64,
          bn_var + l * 64, h, N_);
    } else {
      gat_fused_kernel<false><<<gatBlocks, 256, 0, stream>>>(
          csr_src, csr_eid, row_ptr, edge_attr, xl, xr,
          We + (size_t)l * 1024, att + l * 64, conv_bias + l * 64,
          bn_gamma + l * 64, bn_beta + l * 64, bn_mean + l * 64,
          bn_var + l * 64, h, N_);
    }
  }

  hipMemsetAsync(d_out, 0, (size_t)G_ * 128 * 4, stream);
  lin_pool_kernel<<<(N_ + 63) / 64, 256, 0, stream>>>(
      h, lin_W, lin_b, batch, counts, (float*)d_out, N_);
}